// Round 4
// baseline (519.681 us; speedup 1.0000x reference)
//
#include <hip/hip_runtime.h>
#include <hip/hip_cooperative_groups.h>
#include <math.h>

namespace cg = cooperative_groups;

#define BB 64
#define TT 4096
#define DD 256
#define HH 256
#define NEG_INF_F (-1e9f)

// ws layout (floats):
//   partials[1024*256] @ 0         (1 MB)
//   wkq[BB*DD]         @ 262144
//   ek[BB]             @ 278528
//   e[BB*TT]           @ 278592

// ===== Cooperative fused kernel: colsum -> (mean,q,wkq,ek) -> scores ========
// grid = 1024 blocks x 256 threads (4 blocks/CU guaranteed co-resident via
// __launch_bounds__(256,4) -> VGPR<=128, LDS ~7.5KB). Block j owns the 256-row
// chunk (b=j>>4, chunk=j&15) in BOTH phase A and phase C, so phase C re-reads
// data it itself streamed in phase A: input (256 MiB) == LLC capacity, so the
// re-read is Infinity-Cache-hit instead of HBM.
__global__ __launch_bounds__(256, 4) void k_fused(const float* __restrict__ input,
                                                  const float* __restrict__ Wq,
                                                  const float* __restrict__ bq,
                                                  const float* __restrict__ Wk,
                                                  const float* __restrict__ bk,
                                                  const int* __restrict__ mask,
                                                  const float* __restrict__ rate,
                                                  float* __restrict__ partials,
                                                  float* __restrict__ wkq,
                                                  float* __restrict__ ek,
                                                  float* __restrict__ e_out) {
    cg::grid_group grid = cg::this_grid();
    int j = blockIdx.x;                 // 0..1023
    int b = j >> 4;
    int chunk = j & 15;                 // 16 chunks of 256 rows per batch
    int tid = threadIdx.x;
    int wave = tid >> 6, lane = tid & 63;

    __shared__ __align__(16) float4 sm4[256];   // 4 KB (phase A reduce)
    __shared__ __align__(16) float mr[DD];      // mean (B) / wsh (C)
    __shared__ __align__(16) float qsh[HH];     // q (B) / esh (C)
    __shared__ float red[4];

    // ---------------- Phase A: column partial sums ----------------
    const float4* base = (const float4*)(input + ((size_t)b * TT + chunk * 256) * DD);
    const float4* wbase = base + (size_t)(wave * 64) * 64;   // 64 rows per wave
    float4 acc = make_float4(0.f, 0.f, 0.f, 0.f);
#pragma unroll 8
    for (int r = 0; r < 64; ++r) {
        float4 v = wbase[(size_t)r * 64 + lane];
        acc.x += v.x; acc.y += v.y; acc.z += v.z; acc.w += v.w;
    }
    sm4[tid] = acc;
    __syncthreads();
    if (tid < 64) {
        float4 a0 = sm4[tid], a1 = sm4[tid + 64], a2 = sm4[tid + 128], a3 = sm4[tid + 192];
        float4 r4 = make_float4(a0.x + a1.x + a2.x + a3.x,
                                a0.y + a1.y + a2.y + a3.y,
                                a0.z + a1.z + a2.z + a3.z,
                                a0.w + a1.w + a2.w + a3.w);
        ((float4*)(partials + (size_t)j * 256))[tid] = r4;
    }
    __threadfence();
    grid.sync();

    // ------- Phase B: mean -> q (redundant per chunk); wkq slice; ek -------
    {
        const float* pb = partials + (size_t)b * 16 * 256;
        float s = 0.f;
#pragma unroll
        for (int c = 0; c < 16; ++c) s += pb[c * 256 + tid];   // coalesced, L2-hot
        mr[tid] = s * (1.0f / (float)TT);
        __syncthreads();
        float q = bq[tid];
#pragma unroll 8
        for (int d = 0; d < DD; ++d) q += mr[d] * Wq[d * HH + tid];  // coalesced
        qsh[tid] = q;
        if (chunk == 0) {               // one block per b writes ek
            float p = bk[tid] * q;
#pragma unroll
            for (int off = 32; off > 0; off >>= 1) p += __shfl_down(p, off);
            if (lane == 0) red[wave] = p;
        }
        __syncthreads();                // publishes qsh (and red)
        if (chunk == 0 && tid == 0) ek[b] = red[0] + red[1] + red[2] + red[3];
        // wkq rows [chunk*16, chunk*16+16): 4 rows per wave, coalesced Wk reads
        float4 qv = ((const float4*)qsh)[lane];
#pragma unroll
        for (int i = 0; i < 4; ++i) {
            int d = chunk * 16 + wave * 4 + i;
            float4 wv = ((const float4*)(Wk + (size_t)d * HH))[lane];
            float t = wv.x * qv.x + wv.y * qv.y + wv.z * qv.z + wv.w * qv.w;
#pragma unroll
            for (int off = 32; off > 0; off >>= 1) t += __shfl_down(t, off);
            if (lane == 0) wkq[b * DD + d] = t;
        }
    }
    __threadfence();
    grid.sync();

    // ---------------- Phase C: scores over the SAME chunk (LLC-hot) --------
    {
        float* wsh = mr;                 // reuse LDS
        float* esh = qsh;
        wsh[tid] = wkq[b * DD + tid];
        __syncthreads();
        float4 w4 = ((const float4*)wsh)[lane];
        float ekb = ek[b];
#pragma unroll 4
        for (int r = 0; r < 64; ++r) {
            float4 v = wbase[(size_t)r * 64 + lane];
            float s = v.x * w4.x + v.y * w4.y + v.z * w4.z + v.w * w4.w;
#pragma unroll
            for (int off = 32; off > 0; off >>= 1) s += __shfl_down(s, off);
            if (lane == 0) esh[wave * 64 + r] = s;
        }
        __syncthreads();
        int t = chunk * 256 + tid;
        float e = esh[tid] + ekb;
        int m = mask[b * TT + t];
        if (m != 0) {
            float sg = 1.f / (1.f + expf(e));      // = 1 - sigmoid(e)
            e = e - rate[t] * log1pf(sg * (float)m);
        } else {
            e = NEG_INF_F;
        }
        e_out[b * TT + t] = e;                     // coalesced 256-wide
    }
}

// ---- Final kernel: sparsemax (seeded Michelot) + gather + @Wv + bv ---------
__global__ __launch_bounds__(1024) void k_fin(const float* __restrict__ e_in,
                                              const float* __restrict__ input,
                                              const float* __restrict__ Wv,
                                              const float* __restrict__ bv,
                                              float* __restrict__ out,
                                              float* __restrict__ a_out) {
    int b = blockIdx.x, tid = threadIdx.x;
    int wave = tid >> 6, lane = tid & 63;
    __shared__ float za[TT];                       // 16 KB
    __shared__ int s_supp[TT];                     // 16 KB (worst case all-active)
    __shared__ __align__(16) float part[16 * DD];  // 16 KB
    __shared__ __align__(16) float s_sh[DD];
    __shared__ float redM[16];
    __shared__ float redS[2][16], redC[2][16];
    __shared__ int cnt;

    const float* er = e_in + (size_t)b * TT;
    float z0 = er[tid], z1 = er[tid + 1024], z2 = er[tid + 2048], z3 = er[tid + 3072];
    float lmax = fmaxf(fmaxf(z0, z1), fmaxf(z2, z3));
#pragma unroll
    for (int off = 32; off > 0; off >>= 1) lmax = fmaxf(lmax, __shfl_xor(lmax, off));
    if (lane == 0) redM[wave] = lmax;
    if (tid == 0) cnt = 0;
    __syncthreads();
    float mx = redM[0];
#pragma unroll
    for (int i = 1; i < 16; ++i) mx = fmaxf(mx, redM[i]);  // uniform LDS broadcast
    // clamp to -1: lossless (support always has z-zmax > -1), kills NEG_INF rows
    z0 = fmaxf(z0 - mx, -1.0f); z1 = fmaxf(z1 - mx, -1.0f);
    z2 = fmaxf(z2 - mx, -1.0f); z3 = fmaxf(z3 - mx, -1.0f);
    za[tid] = z0; za[tid + 1024] = z1; za[tid + 2048] = z2; za[tid + 3072] = z3;

    // Michelot fixed point seeded at tau=-1 (support subset of {z > zmax-1}):
    // ~2-4 iterations; one barrier/iter via double-buffered reductions.
    float tau = -1.0f;
    int prevc = -1;
    for (int it = 0; it < 32; ++it) {
        int pb = it & 1;
        float s = 0.f, c = 0.f;
        if (z0 > tau) { s += z0; c += 1.f; }
        if (z1 > tau) { s += z1; c += 1.f; }
        if (z2 > tau) { s += z2; c += 1.f; }
        if (z3 > tau) { s += z3; c += 1.f; }
#pragma unroll
        for (int off = 32; off > 0; off >>= 1) {
            s += __shfl_xor(s, off);
            c += __shfl_xor(c, off);
        }
        if (lane == 0) { redS[pb][wave] = s; redC[pb][wave] = c; }
        __syncthreads();
        float ss = 0.f, cc = 0.f;
#pragma unroll
        for (int i = 0; i < 16; ++i) { ss += redS[pb][i]; cc += redC[pb][i]; }
        tau = (ss - 1.f) / cc;            // identical across all threads
        int ci = (int)cc;
        if (ci == prevc) break;           // set stable => fixed point
        prevc = ci;
    }

    // a, a_out, support list, suma
    float a0 = fmaxf(z0 - tau, 0.f), a1 = fmaxf(z1 - tau, 0.f);
    float a2 = fmaxf(z2 - tau, 0.f), a3 = fmaxf(z3 - tau, 0.f);
    float* ar = a_out + (size_t)b * TT;
    ar[tid] = a0; ar[tid + 1024] = a1; ar[tid + 2048] = a2; ar[tid + 3072] = a3;
    if (a0 > 0.f) s_supp[atomicAdd(&cnt, 1)] = tid;
    if (a1 > 0.f) s_supp[atomicAdd(&cnt, 1)] = tid + 1024;
    if (a2 > 0.f) s_supp[atomicAdd(&cnt, 1)] = tid + 2048;
    if (a3 > 0.f) s_supp[atomicAdd(&cnt, 1)] = tid + 3072;
    float lsum = a0 + a1 + a2 + a3;
#pragma unroll
    for (int off = 32; off > 0; off >>= 1) lsum += __shfl_xor(lsum, off);
    if (lane == 0) redM[wave] = lsum;
    __syncthreads();                      // publishes redM, s_supp, cnt
    float suma = 0.f;
#pragma unroll
    for (int i = 0; i < 16; ++i) suma += redM[i];  // uniform

    // gather: s[d] = sum_{t in supp} a_t * input[b,t,d], waves split supp
    float4 acc = make_float4(0.f, 0.f, 0.f, 0.f);
    int cl = cnt;
    for (int i = wave; i < cl; i += 16) {
        int t = s_supp[i];
        float av = fmaxf(za[t] - tau, 0.f);
        float4 v = ((const float4*)(input + ((size_t)b * TT + t) * DD))[lane];
        acc.x += av * v.x; acc.y += av * v.y; acc.z += av * v.z; acc.w += av * v.w;
    }
    ((float4*)part)[wave * 64 + lane] = acc;
    __syncthreads();
    if (tid < 256) {
        float s = 0.f;
#pragma unroll
        for (int w = 0; w < 16; ++w) s += part[w * 256 + tid];
        s_sh[tid] = s;
    }
    __syncthreads();
    // out[h] = sum_d s[d]*Wv[d][h] + suma*bv[h]; 4 groups of 256 threads split d
    int h = tid & 255;
    int g = tid >> 8;                  // 0..3
    float o = 0.f;
#pragma unroll 8
    for (int d = g * 64; d < g * 64 + 64; ++d) o += s_sh[d] * Wv[(size_t)d * HH + h];
    part[g * 256 + h] = o;
    __syncthreads();
    if (tid < 256) {
        float o4 = part[tid] + part[256 + tid] + part[512 + tid] + part[768 + tid]
                 + suma * bv[tid];
        out[b * HH + tid] = o4;
    }
}

extern "C" void kernel_launch(void* const* d_in, const int* in_sizes, int n_in,
                              void* d_out, int out_size, void* d_ws, size_t ws_size,
                              hipStream_t stream) {
    const float* input = (const float*)d_in[0];
    const int*   mask  = (const int*)d_in[1];
    const float* Wq    = (const float*)d_in[2];
    const float* bq    = (const float*)d_in[3];
    const float* Wk    = (const float*)d_in[4];
    const float* bk    = (const float*)d_in[5];
    const float* Wv    = (const float*)d_in[6];
    const float* bv    = (const float*)d_in[7];
    const float* rate  = (const float*)d_in[8];

    float* out   = (float*)d_out;            // (B,H)
    float* a_out = out + BB * HH;            // (B,T)

    float* ws       = (float*)d_ws;
    float* partials = ws;                    // 1024*256
    float* wkq      = ws + 262144;           // BB*DD
    float* ek       = ws + 278528;           // BB
    float* e        = ws + 278592;           // BB*TT

    void* args[] = {(void*)&input, (void*)&Wq, (void*)&bq, (void*)&Wk, (void*)&bk,
                    (void*)&mask, (void*)&rate,
                    (void*)&partials, (void*)&wkq, (void*)&ek, (void*)&e};
    hipLaunchCooperativeKernel((const void*)k_fused, dim3(1024), dim3(256),
                               args, 0, stream);
    k_fin<<<BB, 1024, 0, stream>>>(e, input, Wv, bv, out, a_out);
}

// Round 5
// 461.604 us; speedup vs baseline: 1.1258x; 1.1258x over previous
//
#include <hip/hip_runtime.h>
#include <math.h>

#define BB 64
#define TT 4096
#define DD 256
#define HH 256
#define NEG_INF_F (-1e9f)

// ws layout (floats):
//   partials[2048*256] @ 0        (2 MB)   32 chunks x 64 b x 256 cols
//   wkq[BB*DD]         @ 524288
//   ek[BB]             @ 540672
//   e[BB*TT]           @ 540736
//   done[BB] (int)     @ 802880

// ----- Kernel 1: column partial sums + folded (mean->q->wkq,ek) tail -------
// grid (chunk=32, b=64), ascending address order. The last-arriving block of
// each b (device-scope atomic flag) computes the k_small work for that b.
__global__ __launch_bounds__(256) void k_colsum(const float* __restrict__ input,
                                                const float* __restrict__ Wq,
                                                const float* __restrict__ bq,
                                                const float* __restrict__ Wk,
                                                const float* __restrict__ bk,
                                                float* __restrict__ partials,
                                                float* __restrict__ wkq,
                                                float* __restrict__ ek,
                                                int* __restrict__ done) {
    int chunk = blockIdx.x;              // 32 chunks of 128 t each
    int b = blockIdx.y;
    int tid = threadIdx.x;
    int wave = tid >> 6, lane = tid & 63;
    int tsub = wave;                     // 0..3
    int d4 = lane;                       // float4 index over D
    const float4* base = (const float4*)(input + ((size_t)b * TT + (size_t)chunk * 128) * DD);
    float4 acc = make_float4(0.f, 0.f, 0.f, 0.f);
#pragma unroll 8
    for (int t = tsub; t < 128; t += 4) {
        float4 v = base[(size_t)t * 64 + d4];
        acc.x += v.x; acc.y += v.y; acc.z += v.z; acc.w += v.w;
    }
    __shared__ __align__(16) float4 sm4[256];
    __shared__ int lastflag;
    sm4[tid] = acc;
    __syncthreads();
    if (tid < 64) {
        float4 a0 = sm4[tid], a1 = sm4[tid + 64], a2 = sm4[tid + 128], a3 = sm4[tid + 192];
        float4 r4 = make_float4(a0.x + a1.x + a2.x + a3.x,
                                a0.y + a1.y + a2.y + a3.y,
                                a0.z + a1.z + a2.z + a3.z,
                                a0.w + a1.w + a2.w + a3.w);
        ((float4*)(partials + ((size_t)b * 32 + chunk) * 256))[tid] = r4;
    }
    __threadfence();                     // release partials (device scope)
    __syncthreads();
    if (tid == 0) lastflag = (atomicAdd(&done[b], 1) == 31);
    __syncthreads();
    if (!lastflag) return;
    __threadfence();                     // acquire: see all 32 chunks' partials

    // ---- folded k_small for this b ----
    __shared__ __align__(16) float mr[DD];
    __shared__ __align__(16) float qsh[HH];
    __shared__ float red[4];
    const float* pb = partials + (size_t)b * 32 * 256;
    float s = 0.f;
#pragma unroll
    for (int c = 0; c < 32; ++c) s += pb[c * 256 + tid];   // coalesced over tid
    mr[tid] = s * (1.0f / (float)TT);
    __syncthreads();
    float q = bq[tid];
#pragma unroll 8
    for (int d = 0; d < DD; ++d) q += mr[d] * Wq[d * HH + tid];  // coalesced
    qsh[tid] = q;
    float p = bk[tid] * q;
#pragma unroll
    for (int off = 32; off > 0; off >>= 1) p += __shfl_down(p, off);
    if (lane == 0) red[wave] = p;
    __syncthreads();                      // publishes qsh and red
    if (tid == 0) ek[b] = red[0] + red[1] + red[2] + red[3];
    // wkq[d] = sum_h Wk[d][h]*q[h]: one wave per 64 d-rows, coalesced Wk reads
    float4 qv = ((const float4*)qsh)[lane];
    for (int i = 0; i < 64; ++i) {
        int d = wave * 64 + i;
        float4 wv = ((const float4*)(Wk + (size_t)d * HH))[lane];
        float t = wv.x * qv.x + wv.y * qv.y + wv.z * qv.z + wv.w * qv.w;
#pragma unroll
        for (int off = 32; off > 0; off >>= 1) t += __shfl_down(t, off);
        if (lane == 0) wkq[b * DD + d] = t;
    }
}

// --------- Kernel 2: e[b,t] = input.wkq + ek, time-miss, mask ---------------
// Descending order (freshest LLC lines first); input==LLC capacity so this
// pass is expected to be largely Infinity-Cache-served. 128 rows/block ->
// 2048 blocks = one occupancy round. 2-row paired reduce chains for ILP.
__global__ __launch_bounds__(256) void k_scores(const float* __restrict__ input,
                                                const float* __restrict__ wkq,
                                                const float* __restrict__ ek,
                                                const int* __restrict__ mask,
                                                const float* __restrict__ rate,
                                                float* __restrict__ e_out) {
    int job = (int)gridDim.x - 1 - (int)blockIdx.x;
    int b = job >> 5;                    // 32 blocks per b
    int t0 = (job & 31) << 7;            // 128 rows per block
    int tid = threadIdx.x;
    int wave = tid >> 6, lane = tid & 63;
    __shared__ __align__(16) float wsh[DD];
    __shared__ float esh[128];
    wsh[tid] = wkq[b * DD + tid];
    __syncthreads();
    float4 w = ((const float4*)wsh)[lane];
    int tbase = t0 + wave * 32;
    const float4* rows = (const float4*)(input + ((size_t)b * TT + tbase) * DD);
#pragma unroll
    for (int r = 0; r < 32; r += 2) {
        float4 v0 = rows[(size_t)r * 64 + lane];
        float4 v1 = rows[(size_t)(r + 1) * 64 + lane];
        float s0 = v0.x * w.x + v0.y * w.y + v0.z * w.z + v0.w * w.w;
        float s1 = v1.x * w.x + v1.y * w.y + v1.z * w.z + v1.w * w.w;
#pragma unroll
        for (int off = 32; off > 0; off >>= 1) {   // two independent chains
            s0 += __shfl_down(s0, off);
            s1 += __shfl_down(s1, off);
        }
        if (lane == 0) { esh[wave * 32 + r] = s0; esh[wave * 32 + r + 1] = s1; }
    }
    __syncthreads();
    if (tid < 128) {
        int t = t0 + tid;
        float e = esh[tid] + ek[b];
        int m = mask[b * TT + t];
        if (m != 0) {
            float sg = 1.f / (1.f + expf(e));      // = 1 - sigmoid(e)
            e = e - rate[t] * log1pf(sg * (float)m);
        } else {
            e = NEG_INF_F;
        }
        e_out[b * TT + t] = e;                     // coalesced 128-wide
    }
}

// ---- Kernel 3: sparsemax (seeded Michelot) + gather + @Wv + bv -------------
__global__ __launch_bounds__(1024) void k_fin(const float* __restrict__ e_in,
                                              const float* __restrict__ input,
                                              const float* __restrict__ Wv,
                                              const float* __restrict__ bv,
                                              float* __restrict__ out,
                                              float* __restrict__ a_out) {
    int b = blockIdx.x, tid = threadIdx.x;
    int wave = tid >> 6, lane = tid & 63;
    __shared__ float za[TT];                       // 16 KB
    __shared__ int s_supp[TT];                     // 16 KB (worst case all-active)
    __shared__ __align__(16) float part[16 * DD];  // 16 KB
    __shared__ __align__(16) float s_sh[DD];
    __shared__ float redM[16];
    __shared__ float redS[2][16], redC[2][16];
    __shared__ int cnt;

    const float* er = e_in + (size_t)b * TT;
    float z0 = er[tid], z1 = er[tid + 1024], z2 = er[tid + 2048], z3 = er[tid + 3072];
    float lmax = fmaxf(fmaxf(z0, z1), fmaxf(z2, z3));
#pragma unroll
    for (int off = 32; off > 0; off >>= 1) lmax = fmaxf(lmax, __shfl_xor(lmax, off));
    if (lane == 0) redM[wave] = lmax;
    if (tid == 0) cnt = 0;
    __syncthreads();
    float mx = redM[0];
#pragma unroll
    for (int i = 1; i < 16; ++i) mx = fmaxf(mx, redM[i]);  // uniform LDS broadcast
    // clamp to -1: lossless (support always has z-zmax > -1), kills NEG_INF rows
    z0 = fmaxf(z0 - mx, -1.0f); z1 = fmaxf(z1 - mx, -1.0f);
    z2 = fmaxf(z2 - mx, -1.0f); z3 = fmaxf(z3 - mx, -1.0f);
    za[tid] = z0; za[tid + 1024] = z1; za[tid + 2048] = z2; za[tid + 3072] = z3;

    // Michelot fixed point seeded at tau=-1 (support subset of {z > zmax-1}):
    // ~2-4 iterations; one barrier/iter via double-buffered reductions.
    float tau = -1.0f;
    int prevc = -1;
    for (int it = 0; it < 32; ++it) {
        int pb = it & 1;
        float s = 0.f, c = 0.f;
        if (z0 > tau) { s += z0; c += 1.f; }
        if (z1 > tau) { s += z1; c += 1.f; }
        if (z2 > tau) { s += z2; c += 1.f; }
        if (z3 > tau) { s += z3; c += 1.f; }
#pragma unroll
        for (int off = 32; off > 0; off >>= 1) {
            s += __shfl_xor(s, off);
            c += __shfl_xor(c, off);
        }
        if (lane == 0) { redS[pb][wave] = s; redC[pb][wave] = c; }
        __syncthreads();
        float ss = 0.f, cc = 0.f;
#pragma unroll
        for (int i = 0; i < 16; ++i) { ss += redS[pb][i]; cc += redC[pb][i]; }
        tau = (ss - 1.f) / cc;            // identical across all threads
        int ci = (int)cc;
        if (ci == prevc) break;           // set stable => fixed point
        prevc = ci;
    }

    // a, a_out, support list, suma
    float a0 = fmaxf(z0 - tau, 0.f), a1 = fmaxf(z1 - tau, 0.f);
    float a2 = fmaxf(z2 - tau, 0.f), a3 = fmaxf(z3 - tau, 0.f);
    float* ar = a_out + (size_t)b * TT;
    ar[tid] = a0; ar[tid + 1024] = a1; ar[tid + 2048] = a2; ar[tid + 3072] = a3;
    if (a0 > 0.f) s_supp[atomicAdd(&cnt, 1)] = tid;
    if (a1 > 0.f) s_supp[atomicAdd(&cnt, 1)] = tid + 1024;
    if (a2 > 0.f) s_supp[atomicAdd(&cnt, 1)] = tid + 2048;
    if (a3 > 0.f) s_supp[atomicAdd(&cnt, 1)] = tid + 3072;
    float lsum = a0 + a1 + a2 + a3;
#pragma unroll
    for (int off = 32; off > 0; off >>= 1) lsum += __shfl_xor(lsum, off);
    if (lane == 0) redM[wave] = lsum;
    __syncthreads();                      // publishes redM, s_supp, cnt
    float suma = 0.f;
#pragma unroll
    for (int i = 0; i < 16; ++i) suma += redM[i];  // uniform

    // gather: s[d] = sum_{t in supp} a_t * input[b,t,d], waves split supp
    float4 acc = make_float4(0.f, 0.f, 0.f, 0.f);
    int cl = cnt;
    for (int i = wave; i < cl; i += 16) {
        int t = s_supp[i];
        float av = fmaxf(za[t] - tau, 0.f);
        float4 v = ((const float4*)(input + ((size_t)b * TT + t) * DD))[lane];
        acc.x += av * v.x; acc.y += av * v.y; acc.z += av * v.z; acc.w += av * v.w;
    }
    ((float4*)part)[wave * 64 + lane] = acc;
    __syncthreads();
    if (tid < 256) {
        float s = 0.f;
#pragma unroll
        for (int w = 0; w < 16; ++w) s += part[w * 256 + tid];
        s_sh[tid] = s;
    }
    __syncthreads();
    // out[h] = sum_d s[d]*Wv[d][h] + suma*bv[h]; 4 groups of 256 threads split d
    int h = tid & 255;
    int g = tid >> 8;                  // 0..3
    float o = 0.f;
#pragma unroll 8
    for (int d = g * 64; d < g * 64 + 64; ++d) o += s_sh[d] * Wv[(size_t)d * HH + h];
    part[g * 256 + h] = o;
    __syncthreads();
    if (tid < 256) {
        float o4 = part[tid] + part[256 + tid] + part[512 + tid] + part[768 + tid]
                 + suma * bv[tid];
        out[b * HH + tid] = o4;
    }
}

extern "C" void kernel_launch(void* const* d_in, const int* in_sizes, int n_in,
                              void* d_out, int out_size, void* d_ws, size_t ws_size,
                              hipStream_t stream) {
    const float* input = (const float*)d_in[0];
    const int*   mask  = (const int*)d_in[1];
    const float* Wq    = (const float*)d_in[2];
    const float* bq    = (const float*)d_in[3];
    const float* Wk    = (const float*)d_in[4];
    const float* bk    = (const float*)d_in[5];
    const float* Wv    = (const float*)d_in[6];
    const float* bv    = (const float*)d_in[7];
    const float* rate  = (const float*)d_in[8];

    float* out   = (float*)d_out;            // (B,H)
    float* a_out = out + BB * HH;            // (B,T)

    float* ws       = (float*)d_ws;
    float* partials = ws;                    // 2048*256
    float* wkq      = ws + 524288;           // BB*DD
    float* ek       = ws + 540672;           // BB
    float* e        = ws + 540736;           // BB*TT
    int*   done     = (int*)(ws + 802880);   // BB

    hipMemsetAsync(done, 0, BB * sizeof(int), stream);
    k_colsum<<<dim3(32, BB), 256, 0, stream>>>(input, Wq, bq, Wk, bk,
                                               partials, wkq, ek, done);
    k_scores<<<(BB * TT) / 128, 256, 0, stream>>>(input, wkq, ek, mask, rate, e);
    k_fin<<<BB, 1024, 0, stream>>>(e, input, Wv, bv, out, a_out);
}

// Round 6
// 206.214 us; speedup vs baseline: 2.5201x; 2.2385x over previous
//
#include <hip/hip_runtime.h>
#include <math.h>

#define BB 64
#define TT 4096
#define DD 256
#define HH 256
#define NEG_INF_F (-1e9f)

// ws layout (floats):
//   meansum[BB*DD] @ 0        (64 KB, atomic-accumulated; memset each launch)
//   done[BB] (int) @ 16384    (memset each launch)
//   wkq[BB*DD]     @ 16448
//   ek[BB]         @ 32832
//   e[BB*TT]       @ 32896

// ----- Kernel 1: column sums via LLC atomics + fenceless last-block tail ----
// 16 chunks x 256 rows per b. Atomic adds land at the coherent LLC point, so
// NO release fence is needed (R5's 2048 release fences were the disaster).
// Each block orders its atomics before the done[] increment with a pure
// s_waitcnt (no cache maintenance). Only the 64 tail blocks pay an acquire
// __threadfence() before plain-loading the accumulated sums.
__global__ __launch_bounds__(256) void k_pass1(const float* __restrict__ input,
                                               const float* __restrict__ Wq,
                                               const float* __restrict__ bq,
                                               const float* __restrict__ Wk,
                                               const float* __restrict__ bk,
                                               float* __restrict__ meansum,
                                               float* __restrict__ wkq,
                                               float* __restrict__ ek,
                                               int* __restrict__ done) {
    int chunk = blockIdx.x;              // 0..15, 256 rows each
    int b = blockIdx.y;
    int tid = threadIdx.x;
    int wave = tid >> 6, lane = tid & 63;

    const float4* base = (const float4*)(input + ((size_t)b * TT + chunk * 256) * DD);
    const float4* wbase = base + (size_t)(wave * 64) * 64;   // 64 rows per wave
    float4 acc = make_float4(0.f, 0.f, 0.f, 0.f);
#pragma unroll 8
    for (int r = 0; r < 64; ++r) {
        float4 v = wbase[(size_t)r * 64 + lane];
        acc.x += v.x; acc.y += v.y; acc.z += v.z; acc.w += v.w;
    }
    __shared__ __align__(16) float4 sm4[256];
    __shared__ int lastflag;
    sm4[tid] = acc;
    __syncthreads();
    if (tid < 64) {
        float4 a0 = sm4[tid], a1 = sm4[tid + 64], a2 = sm4[tid + 128], a3 = sm4[tid + 192];
        atomicAdd(&meansum[b * DD + tid * 4 + 0], a0.x + a1.x + a2.x + a3.x);
        atomicAdd(&meansum[b * DD + tid * 4 + 1], a0.y + a1.y + a2.y + a3.y);
        atomicAdd(&meansum[b * DD + tid * 4 + 2], a0.z + a1.z + a2.z + a3.z);
        atomicAdd(&meansum[b * DD + tid * 4 + 3], a0.w + a1.w + a2.w + a3.w);
    }
    // Pure wait: my wave's atomics have reached the LLC. No cache flush.
    asm volatile("s_waitcnt vmcnt(0)" ::: "memory");
    __syncthreads();                      // all waves past their waitcnt
    if (tid == 0) lastflag = (atomicAdd(&done[b], 1) == 15);
    __syncthreads();
    if (!lastflag) return;

    // ---- tail (1 block per b): acquire, then mean -> q -> wkq, ek ----
    __threadfence();                      // invalidate local caches; LLC is truth
    __shared__ __align__(16) float mr[DD];
    __shared__ __align__(16) float qsh[HH];
    __shared__ float red[4];
    mr[tid] = meansum[b * DD + tid] * (1.0f / (float)TT);
    __syncthreads();
    float q = bq[tid];
#pragma unroll 8
    for (int d = 0; d < DD; ++d) q += mr[d] * Wq[d * HH + tid];  // coalesced
    qsh[tid] = q;
    float p = bk[tid] * q;
#pragma unroll
    for (int off = 32; off > 0; off >>= 1) p += __shfl_down(p, off);
    if (lane == 0) red[wave] = p;
    __syncthreads();                      // publishes qsh and red
    if (tid == 0) ek[b] = red[0] + red[1] + red[2] + red[3];
    float4 qv = ((const float4*)qsh)[lane];
    for (int i = 0; i < 64; ++i) {
        int d = wave * 64 + i;
        float4 wv = ((const float4*)(Wk + (size_t)d * HH))[lane];
        float t = wv.x * qv.x + wv.y * qv.y + wv.z * qv.z + wv.w * qv.w;
#pragma unroll
        for (int off = 32; off > 0; off >>= 1) t += __shfl_down(t, off);
        if (lane == 0) wkq[b * DD + d] = t;
    }
}

// --------- Kernel 2: e[b,t] = input.wkq + ek, time-miss, mask ---------------
// Descending order: freshest LLC lines first; input ~= LLC capacity and stays
// partially resident across replays, so much of this pass is LLC-served.
__global__ __launch_bounds__(256) void k_scores(const float* __restrict__ input,
                                                const float* __restrict__ wkq,
                                                const float* __restrict__ ek,
                                                const int* __restrict__ mask,
                                                const float* __restrict__ rate,
                                                float* __restrict__ e_out) {
    int job = (int)gridDim.x - 1 - (int)blockIdx.x;
    int b = job >> 5;                    // 32 blocks per b
    int t0 = (job & 31) << 7;            // 128 rows per block
    int tid = threadIdx.x;
    int wave = tid >> 6, lane = tid & 63;
    __shared__ __align__(16) float wsh[DD];
    __shared__ float esh[128];
    wsh[tid] = wkq[b * DD + tid];
    __syncthreads();
    float4 w = ((const float4*)wsh)[lane];
    int tbase = t0 + wave * 32;
    const float4* rows = (const float4*)(input + ((size_t)b * TT + tbase) * DD);
#pragma unroll
    for (int r = 0; r < 32; r += 2) {
        float4 v0 = rows[(size_t)r * 64 + lane];
        float4 v1 = rows[(size_t)(r + 1) * 64 + lane];
        float s0 = v0.x * w.x + v0.y * w.y + v0.z * w.z + v0.w * w.w;
        float s1 = v1.x * w.x + v1.y * w.y + v1.z * w.z + v1.w * w.w;
#pragma unroll
        for (int off = 32; off > 0; off >>= 1) {   // two independent chains
            s0 += __shfl_down(s0, off);
            s1 += __shfl_down(s1, off);
        }
        if (lane == 0) { esh[wave * 32 + r] = s0; esh[wave * 32 + r + 1] = s1; }
    }
    __syncthreads();
    if (tid < 128) {
        int t = t0 + tid;
        float e = esh[tid] + ek[b];
        int m = mask[b * TT + t];
        if (m != 0) {
            float sg = 1.f / (1.f + expf(e));      // = 1 - sigmoid(e)
            e = e - rate[t] * log1pf(sg * (float)m);
        } else {
            e = NEG_INF_F;
        }
        e_out[b * TT + t] = e;                     // coalesced 128-wide
    }
}

// ---- Kernel 3: sparsemax (seeded Michelot) + gather + @Wv + bv -------------
__global__ __launch_bounds__(1024) void k_fin(const float* __restrict__ e_in,
                                              const float* __restrict__ input,
                                              const float* __restrict__ Wv,
                                              const float* __restrict__ bv,
                                              float* __restrict__ out,
                                              float* __restrict__ a_out) {
    int b = blockIdx.x, tid = threadIdx.x;
    int wave = tid >> 6, lane = tid & 63;
    __shared__ float za[TT];                       // 16 KB
    __shared__ int s_supp[TT];                     // 16 KB (worst case all-active)
    __shared__ __align__(16) float part[16 * DD];  // 16 KB
    __shared__ __align__(16) float s_sh[DD];
    __shared__ float redM[16];
    __shared__ float redS[2][16], redC[2][16];
    __shared__ int cnt;

    const float* er = e_in + (size_t)b * TT;
    float z0 = er[tid], z1 = er[tid + 1024], z2 = er[tid + 2048], z3 = er[tid + 3072];
    float lmax = fmaxf(fmaxf(z0, z1), fmaxf(z2, z3));
#pragma unroll
    for (int off = 32; off > 0; off >>= 1) lmax = fmaxf(lmax, __shfl_xor(lmax, off));
    if (lane == 0) redM[wave] = lmax;
    if (tid == 0) cnt = 0;
    __syncthreads();
    float mx = redM[0];
#pragma unroll
    for (int i = 1; i < 16; ++i) mx = fmaxf(mx, redM[i]);  // uniform LDS broadcast
    // clamp to -1: lossless (support always has z-zmax > -1), kills NEG_INF rows
    z0 = fmaxf(z0 - mx, -1.0f); z1 = fmaxf(z1 - mx, -1.0f);
    z2 = fmaxf(z2 - mx, -1.0f); z3 = fmaxf(z3 - mx, -1.0f);
    za[tid] = z0; za[tid + 1024] = z1; za[tid + 2048] = z2; za[tid + 3072] = z3;

    // Michelot fixed point seeded at tau=-1 (support subset of {z > zmax-1}):
    // ~2-4 iterations; one barrier/iter via double-buffered reductions.
    float tau = -1.0f;
    int prevc = -1;
    for (int it = 0; it < 32; ++it) {
        int pb = it & 1;
        float s = 0.f, c = 0.f;
        if (z0 > tau) { s += z0; c += 1.f; }
        if (z1 > tau) { s += z1; c += 1.f; }
        if (z2 > tau) { s += z2; c += 1.f; }
        if (z3 > tau) { s += z3; c += 1.f; }
#pragma unroll
        for (int off = 32; off > 0; off >>= 1) {
            s += __shfl_xor(s, off);
            c += __shfl_xor(c, off);
        }
        if (lane == 0) { redS[pb][wave] = s; redC[pb][wave] = c; }
        __syncthreads();
        float ss = 0.f, cc = 0.f;
#pragma unroll
        for (int i = 0; i < 16; ++i) { ss += redS[pb][i]; cc += redC[pb][i]; }
        tau = (ss - 1.f) / cc;            // identical across all threads
        int ci = (int)cc;
        if (ci == prevc) break;           // set stable => fixed point
        prevc = ci;
    }

    // a, a_out, support list, suma
    float a0 = fmaxf(z0 - tau, 0.f), a1 = fmaxf(z1 - tau, 0.f);
    float a2 = fmaxf(z2 - tau, 0.f), a3 = fmaxf(z3 - tau, 0.f);
    float* ar = a_out + (size_t)b * TT;
    ar[tid] = a0; ar[tid + 1024] = a1; ar[tid + 2048] = a2; ar[tid + 3072] = a3;
    if (a0 > 0.f) s_supp[atomicAdd(&cnt, 1)] = tid;
    if (a1 > 0.f) s_supp[atomicAdd(&cnt, 1)] = tid + 1024;
    if (a2 > 0.f) s_supp[atomicAdd(&cnt, 1)] = tid + 2048;
    if (a3 > 0.f) s_supp[atomicAdd(&cnt, 1)] = tid + 3072;
    float lsum = a0 + a1 + a2 + a3;
#pragma unroll
    for (int off = 32; off > 0; off >>= 1) lsum += __shfl_xor(lsum, off);
    if (lane == 0) redM[wave] = lsum;
    __syncthreads();                      // publishes redM, s_supp, cnt
    float suma = 0.f;
#pragma unroll
    for (int i = 0; i < 16; ++i) suma += redM[i];  // uniform

    // gather: s[d] = sum_{t in supp} a_t * input[b,t,d], waves split supp
    float4 acc = make_float4(0.f, 0.f, 0.f, 0.f);
    int cl = cnt;
    for (int i = wave; i < cl; i += 16) {
        int t = s_supp[i];
        float av = fmaxf(za[t] - tau, 0.f);
        float4 v = ((const float4*)(input + ((size_t)b * TT + t) * DD))[lane];
        acc.x += av * v.x; acc.y += av * v.y; acc.z += av * v.z; acc.w += av * v.w;
    }
    ((float4*)part)[wave * 64 + lane] = acc;
    __syncthreads();
    if (tid < 256) {
        float s = 0.f;
#pragma unroll
        for (int w = 0; w < 16; ++w) s += part[w * 256 + tid];
        s_sh[tid] = s;
    }
    __syncthreads();
    // out[h] = sum_d s[d]*Wv[d][h] + suma*bv[h]; 4 groups of 256 threads split d
    int h = tid & 255;
    int g = tid >> 8;                  // 0..3
    float o = 0.f;
#pragma unroll 8
    for (int d = g * 64; d < g * 64 + 64; ++d) o += s_sh[d] * Wv[(size_t)d * HH + h];
    part[g * 256 + h] = o;
    __syncthreads();
    if (tid < 256) {
        float o4 = part[tid] + part[256 + tid] + part[512 + tid] + part[768 + tid]
                 + suma * bv[tid];
        out[b * HH + tid] = o4;
    }
}

extern "C" void kernel_launch(void* const* d_in, const int* in_sizes, int n_in,
                              void* d_out, int out_size, void* d_ws, size_t ws_size,
                              hipStream_t stream) {
    const float* input = (const float*)d_in[0];
    const int*   mask  = (const int*)d_in[1];
    const float* Wq    = (const float*)d_in[2];
    const float* bq    = (const float*)d_in[3];
    const float* Wk    = (const float*)d_in[4];
    const float* bk    = (const float*)d_in[5];
    const float* Wv    = (const float*)d_in[6];
    const float* bv    = (const float*)d_in[7];
    const float* rate  = (const float*)d_in[8];

    float* out   = (float*)d_out;            // (B,H)
    float* a_out = out + BB * HH;            // (B,T)

    float* ws      = (float*)d_ws;
    float* meansum = ws;                     // BB*DD @ 0
    int*   done    = (int*)(ws + 16384);     // BB
    float* wkq     = ws + 16448;             // BB*DD
    float* ek      = ws + 32832;             // BB
    float* e       = ws + 32896;             // BB*TT

    // zero meansum + done in one contiguous memset (graph-safe)
    hipMemsetAsync(meansum, 0, (BB * DD + BB) * sizeof(float), stream);
    k_pass1<<<dim3(16, BB), 256, 0, stream>>>(input, Wq, bq, Wk, bk,
                                              meansum, wkq, ek, done);
    k_scores<<<(BB * TT) / 128, 256, 0, stream>>>(input, wkq, ek, mask, rate, e);
    k_fin<<<BB, 1024, 0, stream>>>(e, input, Wv, bv, out, a_out);
}

// Round 7
// 159.044 us; speedup vs baseline: 3.2675x; 1.2966x over previous
//
#include <hip/hip_runtime.h>
#include <math.h>

#define BB 64
#define TT 4096
#define DD 256
#define HH 256
#define NEG_INF_F (-1e9f)

// ws layout (floats):
//   partials[2048*256] @ 0        (2 MB)
//   wkq[BB*DD]         @ 524288
//   ek[BB]             @ 540672
//   e[BB*TT]           @ 540736

// ---------------- Kernel 1: per-chunk column partial sums -------------------
// (byte-identical to the proven R3 version: 2048 blocks, full occupancy,
//  ascending address order; no atomics, no fences, no memset needed)
__global__ __launch_bounds__(256) void k_colsum(const float* __restrict__ input,
                                                float* __restrict__ partials) {
    int chunk = blockIdx.x;              // 32 chunks of 128 t each
    int b = blockIdx.y;
    int tid = threadIdx.x;
    int tsub = tid >> 6;                 // 0..3
    int d4 = tid & 63;                   // float4 index over D
    const float4* base = (const float4*)(input + ((size_t)b * TT + (size_t)chunk * 128) * DD);
    float4 acc = make_float4(0.f, 0.f, 0.f, 0.f);
#pragma unroll 8
    for (int t = tsub; t < 128; t += 4) {
        float4 v = base[(size_t)t * 64 + d4];
        acc.x += v.x; acc.y += v.y; acc.z += v.z; acc.w += v.w;
    }
    __shared__ float4 sm[256];
    sm[tid] = acc;
    __syncthreads();
    if (tid < 64) {
        float4 a0 = sm[tid], a1 = sm[tid + 64], a2 = sm[tid + 128], a3 = sm[tid + 192];
        float4 r = make_float4(a0.x + a1.x + a2.x + a3.x,
                               a0.y + a1.y + a2.y + a3.y,
                               a0.z + a1.z + a2.z + a3.z,
                               a0.w + a1.w + a2.w + a3.w);
        ((float4*)(partials + ((size_t)b * 32 + chunk) * 256))[tid] = r;
    }
}

// --- Kernel 2: reduce partials -> mean; q = mean@Wq+bq ; wkq = Wk@q ; ek ----
__global__ __launch_bounds__(256) void k_small(const float* __restrict__ partials,
                                               const float* __restrict__ Wq,
                                               const float* __restrict__ bq,
                                               const float* __restrict__ Wk,
                                               const float* __restrict__ bk,
                                               float* __restrict__ wkq,
                                               float* __restrict__ ek) {
    int b = blockIdx.x, tid = threadIdx.x;
    int wave = tid >> 6, lane = tid & 63;
    __shared__ __align__(16) float mr[DD];
    __shared__ __align__(16) float qsh[HH];
    __shared__ float red[4];
    const float* pb = partials + (size_t)b * 32 * 256;
    float s = 0.f;
#pragma unroll
    for (int c = 0; c < 32; ++c) s += pb[c * 256 + tid];   // coalesced over tid
    mr[tid] = s * (1.0f / (float)TT);
    __syncthreads();
    float acc = bq[tid];
#pragma unroll 8
    for (int d = 0; d < DD; ++d) acc += mr[d] * Wq[d * HH + tid];  // coalesced
    qsh[tid] = acc;
    float p = bk[tid] * acc;
#pragma unroll
    for (int off = 32; off > 0; off >>= 1) p += __shfl_down(p, off);
    if (lane == 0) red[wave] = p;
    __syncthreads();                      // also publishes qsh
    if (tid == 0) ek[b] = red[0] + red[1] + red[2] + red[3];
    // wkq[d] = sum_h Wk[d][h]*q[h]: one wave per d -> coalesced Wk row reads
    float4 qv = ((const float4*)qsh)[lane];
    for (int i = 0; i < 64; ++i) {
        int d = wave * 64 + i;
        float4 wv = ((const float4*)(Wk + (size_t)d * HH))[lane];
        float t = wv.x * qv.x + wv.y * qv.y + wv.z * qv.z + wv.w * qv.w;
#pragma unroll
        for (int off = 32; off > 0; off >>= 1) t += __shfl_down(t, off);
        if (lane == 0) wkq[b * DD + d] = t;
    }
}

// --------- Kernel 3: e[b,t] = input.wkq + ek, time-miss, mask ---------------
// Descending order (freshest LLC lines first). 128 rows/block -> 2048 blocks
// = one full occupancy round. 2-row paired shfl chains for ILP.
__global__ __launch_bounds__(256) void k_scores(const float* __restrict__ input,
                                                const float* __restrict__ wkq,
                                                const float* __restrict__ ek,
                                                const int* __restrict__ mask,
                                                const float* __restrict__ rate,
                                                float* __restrict__ e_out) {
    int job = (int)gridDim.x - 1 - (int)blockIdx.x;
    int b = job >> 5;                    // 32 blocks per b
    int t0 = (job & 31) << 7;            // 128 rows per block
    int tid = threadIdx.x;
    int wave = tid >> 6, lane = tid & 63;
    __shared__ __align__(16) float wsh[DD];
    __shared__ float esh[128];
    wsh[tid] = wkq[b * DD + tid];
    __syncthreads();
    float4 w = ((const float4*)wsh)[lane];
    int tbase = t0 + wave * 32;
    const float4* rows = (const float4*)(input + ((size_t)b * TT + tbase) * DD);
#pragma unroll
    for (int r = 0; r < 32; r += 2) {
        float4 v0 = rows[(size_t)r * 64 + lane];
        float4 v1 = rows[(size_t)(r + 1) * 64 + lane];
        float s0 = v0.x * w.x + v0.y * w.y + v0.z * w.z + v0.w * w.w;
        float s1 = v1.x * w.x + v1.y * w.y + v1.z * w.z + v1.w * w.w;
#pragma unroll
        for (int off = 32; off > 0; off >>= 1) {   // two independent chains
            s0 += __shfl_down(s0, off);
            s1 += __shfl_down(s1, off);
        }
        if (lane == 0) { esh[wave * 32 + r] = s0; esh[wave * 32 + r + 1] = s1; }
    }
    __syncthreads();
    if (tid < 128) {
        int t = t0 + tid;
        float e = esh[tid] + ek[b];
        int m = mask[b * TT + t];
        if (m != 0) {
            float sg = 1.f / (1.f + expf(e));      // = 1 - sigmoid(e)
            e = e - rate[t] * log1pf(sg * (float)m);
        } else {
            e = NEG_INF_F;
        }
        e_out[b * TT + t] = e;                     // coalesced 128-wide
    }
}

// ---- Kernel 4: sparsemax (seeded Michelot) + gather + @Wv + bv -------------
__global__ __launch_bounds__(1024) void k_fin(const float* __restrict__ e_in,
                                              const float* __restrict__ input,
                                              const float* __restrict__ Wv,
                                              const float* __restrict__ bv,
                                              float* __restrict__ out,
                                              float* __restrict__ a_out) {
    int b = blockIdx.x, tid = threadIdx.x;
    int wave = tid >> 6, lane = tid & 63;
    __shared__ float za[TT];                       // 16 KB
    __shared__ int s_supp[TT];                     // 16 KB (worst case all-active)
    __shared__ __align__(16) float part[16 * DD];  // 16 KB
    __shared__ __align__(16) float s_sh[DD];
    __shared__ float redM[16];
    __shared__ float redS[2][16], redC[2][16];
    __shared__ int cnt;

    const float* er = e_in + (size_t)b * TT;
    float z0 = er[tid], z1 = er[tid + 1024], z2 = er[tid + 2048], z3 = er[tid + 3072];
    float lmax = fmaxf(fmaxf(z0, z1), fmaxf(z2, z3));
#pragma unroll
    for (int off = 32; off > 0; off >>= 1) lmax = fmaxf(lmax, __shfl_xor(lmax, off));
    if (lane == 0) redM[wave] = lmax;
    if (tid == 0) cnt = 0;
    __syncthreads();
    float mx = redM[0];
#pragma unroll
    for (int i = 1; i < 16; ++i) mx = fmaxf(mx, redM[i]);  // uniform LDS broadcast
    // clamp to -1: lossless (support always has z-zmax > -1), kills NEG_INF rows
    z0 = fmaxf(z0 - mx, -1.0f); z1 = fmaxf(z1 - mx, -1.0f);
    z2 = fmaxf(z2 - mx, -1.0f); z3 = fmaxf(z3 - mx, -1.0f);
    za[tid] = z0; za[tid + 1024] = z1; za[tid + 2048] = z2; za[tid + 3072] = z3;

    // Michelot fixed point seeded at tau=-1 (support subset of {z > zmax-1}):
    // ~2-4 iterations; one barrier/iter via double-buffered reductions.
    float tau = -1.0f;
    int prevc = -1;
    for (int it = 0; it < 32; ++it) {
        int pb = it & 1;
        float s = 0.f, c = 0.f;
        if (z0 > tau) { s += z0; c += 1.f; }
        if (z1 > tau) { s += z1; c += 1.f; }
        if (z2 > tau) { s += z2; c += 1.f; }
        if (z3 > tau) { s += z3; c += 1.f; }
#pragma unroll
        for (int off = 32; off > 0; off >>= 1) {
            s += __shfl_xor(s, off);
            c += __shfl_xor(c, off);
        }
        if (lane == 0) { redS[pb][wave] = s; redC[pb][wave] = c; }
        __syncthreads();
        float ss = 0.f, cc = 0.f;
#pragma unroll
        for (int i = 0; i < 16; ++i) { ss += redS[pb][i]; cc += redC[pb][i]; }
        tau = (ss - 1.f) / cc;            // identical across all threads
        int ci = (int)cc;
        if (ci == prevc) break;           // set stable => fixed point
        prevc = ci;
    }

    // a, a_out, support list, suma
    float a0 = fmaxf(z0 - tau, 0.f), a1 = fmaxf(z1 - tau, 0.f);
    float a2 = fmaxf(z2 - tau, 0.f), a3 = fmaxf(z3 - tau, 0.f);
    float* ar = a_out + (size_t)b * TT;
    ar[tid] = a0; ar[tid + 1024] = a1; ar[tid + 2048] = a2; ar[tid + 3072] = a3;
    if (a0 > 0.f) s_supp[atomicAdd(&cnt, 1)] = tid;
    if (a1 > 0.f) s_supp[atomicAdd(&cnt, 1)] = tid + 1024;
    if (a2 > 0.f) s_supp[atomicAdd(&cnt, 1)] = tid + 2048;
    if (a3 > 0.f) s_supp[atomicAdd(&cnt, 1)] = tid + 3072;
    float lsum = a0 + a1 + a2 + a3;
#pragma unroll
    for (int off = 32; off > 0; off >>= 1) lsum += __shfl_xor(lsum, off);
    if (lane == 0) redM[wave] = lsum;
    __syncthreads();                      // publishes redM, s_supp, cnt
    float suma = 0.f;
#pragma unroll
    for (int i = 0; i < 16; ++i) suma += redM[i];  // uniform

    // gather: s[d] = sum_{t in supp} a_t * input[b,t,d], waves split supp
    float4 acc = make_float4(0.f, 0.f, 0.f, 0.f);
    int cl = cnt;
    for (int i = wave; i < cl; i += 16) {
        int t = s_supp[i];
        float av = fmaxf(za[t] - tau, 0.f);
        float4 v = ((const float4*)(input + ((size_t)b * TT + t) * DD))[lane];
        acc.x += av * v.x; acc.y += av * v.y; acc.z += av * v.z; acc.w += av * v.w;
    }
    ((float4*)part)[wave * 64 + lane] = acc;
    __syncthreads();
    if (tid < 256) {
        float s = 0.f;
#pragma unroll
        for (int w = 0; w < 16; ++w) s += part[w * 256 + tid];
        s_sh[tid] = s;
    }
    __syncthreads();
    // out[h] = sum_d s[d]*Wv[d][h] + suma*bv[h]; 4 groups of 256 threads split d
    int h = tid & 255;
    int g = tid >> 8;                  // 0..3
    float o = 0.f;
#pragma unroll 8
    for (int d = g * 64; d < g * 64 + 64; ++d) o += s_sh[d] * Wv[(size_t)d * HH + h];
    part[g * 256 + h] = o;
    __syncthreads();
    if (tid < 256) {
        float o4 = part[tid] + part[256 + tid] + part[512 + tid] + part[768 + tid]
                 + suma * bv[tid];
        out[b * HH + tid] = o4;
    }
}

extern "C" void kernel_launch(void* const* d_in, const int* in_sizes, int n_in,
                              void* d_out, int out_size, void* d_ws, size_t ws_size,
                              hipStream_t stream) {
    const float* input = (const float*)d_in[0];
    const int*   mask  = (const int*)d_in[1];
    const float* Wq    = (const float*)d_in[2];
    const float* bq    = (const float*)d_in[3];
    const float* Wk    = (const float*)d_in[4];
    const float* bk    = (const float*)d_in[5];
    const float* Wv    = (const float*)d_in[6];
    const float* bv    = (const float*)d_in[7];
    const float* rate  = (const float*)d_in[8];

    float* out   = (float*)d_out;            // (B,H)
    float* a_out = out + BB * HH;            // (B,T)

    float* ws       = (float*)d_ws;
    float* partials = ws;                    // 2048*256
    float* wkq      = ws + 524288;           // BB*DD
    float* ek       = ws + 540672;           // BB
    float* e        = ws + 540736;           // BB*TT

    k_colsum<<<dim3(32, BB), 256, 0, stream>>>(input, partials);
    k_small<<<BB, 256, 0, stream>>>(partials, Wq, bq, Wk, bk, wkq, ek);
    k_scores<<<(BB * TT) / 128, 256, 0, stream>>>(input, wkq, ek, mask, rate, e);
    k_fin<<<BB, 1024, 0, stream>>>(e, input, Wv, bv, out, a_out);
}